// Round 6
// baseline (73.776 us; speedup 1.0000x reference)
//
#include <hip/hip_runtime.h>
#include <stdint.h>
#include <math.h>

#define ROWS 4096
#define COLS 11008
#define GPR  86            // groups per row
#define NV   (COLS / 4)    // 2752 float4 per row
#define NFULL 5            // 5 full steps of 512 float4 (2560), tail = 192

typedef float f32x4 __attribute__((ext_vector_type(4)));

// ---------------------------------------------------------------------------
// Kernel 1: build jgrp[k] = invcol[k] >> 7  (uint8, 0..85) into d_ws.
// int64-vs-int32 detection: for little-endian int64 values < 2^32 every odd
// int32 word is 0; an int32 permutation of 0..11007 has at most one zero
// among the 16 sampled odd words.
// ---------------------------------------------------------------------------
__global__ void build_jgrp_kernel(const int32_t* __restrict__ invcol_raw,
                                  uint8_t* __restrict__ jgrp) {
    bool is64 = true;
    #pragma unroll
    for (int i = 1; i < 32; i += 2) {
        if (invcol_raw[i] != 0) { is64 = false; }
    }
    int k = blockIdx.x * blockDim.x + threadIdx.x;
    if (k < COLS) {
        int j = is64 ? invcol_raw[2 * k] : invcol_raw[k];
        jgrp[k] = (uint8_t)(j >> 7);
    }
}

// ---------------------------------------------------------------------------
// Kernel 2: elementwise quant-dequant, f64-round-faithful, rcp fast path,
// 2-deep software pipeline (two float4 + two uchar4 + 8 param ds_reads in
// flight per thread) — R5 showed no pipe saturated (VALU 16%, LDS ~33%,
// HBM 67%): latency-limited, so double the MLP.
//   out = clip(round(x/s), -rzp, qmax-rzp) * s     (exact: ints < 2^24)
// Fast path: q0 = x*(1/s); if within ~10 ulp of a half-integer boundary
// (rate ~7e-6) redo in f64 (gave absmax 0.0 in R3/R5).
// ---------------------------------------------------------------------------
__device__ __forceinline__ float qdq(float v, float4 p) {
    float q0 = __fmul_rn(v, p.y);
    float t  = rintf(q0);
    float d  = fabsf(fabsf(q0 - t) - 0.5f);         // distance to nearest x.5
    if (d <= fabsf(q0) * 1.2e-6f + 1e-30f) {        // ~10 ulp guard band
        t = (float)rint((double)v / (double)p.x);   // |t| < 2^24: cast exact
    }
    t = fminf(fmaxf(t, p.z), p.w);
    return __fmul_rn(t, p.x);
}

__global__ __launch_bounds__(256) void quantdeq_kernel(
        const float*   __restrict__ x,
        const float*   __restrict__ scale,
        const float*   __restrict__ zp,
        const int32_t* __restrict__ qmax,
        const uint8_t* __restrict__ jgrp,
        float*         __restrict__ out) {
    __shared__ float4 lp[GPR];

    const int row = blockIdx.x;
    const int tid = threadIdx.x;

    if (tid < GPR) {
        const int gi = row * GPR + tid;
        float s   = fminf(fmaxf(scale[gi], 1e-4f), 1e4f);
        float rs  = __fdiv_rn(1.0f, s);
        float qmf = (float)qmax[gi];
        float rzp = fminf(fmaxf(rintf(zp[gi]), 0.0f), qmf);
        lp[tid] = make_float4(s, rs, -rzp, qmf - rzp);
    }
    __syncthreads();

    const float4* __restrict__ xrow = reinterpret_cast<const float4*>(x + (size_t)row * COLS);
    f32x4*        __restrict__ orow = reinterpret_cast<f32x4*>(out + (size_t)row * COLS);
    const uchar4* __restrict__ jg4  = reinterpret_cast<const uchar4*>(jgrp);

    // pair layout: step covers 512 float4; thread owns t0=base+2*tid, t0+1.
    int    t0 = 2 * tid;
    float4 v0 = xrow[t0],     v1 = xrow[t0 + 1];
    uchar4 g0 = jg4[t0],      g1 = jg4[t0 + 1];

    int base = 0;
    #pragma unroll
    for (int i = 0; i < NFULL; ++i) {
        float4 w0, w1; uchar4 h0, h1;
        if (i < NFULL - 1) {                       // preload next pair
            int n0 = base + 512 + 2 * tid;
            w0 = xrow[n0];     w1 = xrow[n0 + 1];
            h0 = jg4[n0];      h1 = jg4[n0 + 1];
        } else if (tid < NV - NFULL * 512) {       // preload tail (192)
            int n0 = NFULL * 512 + tid;
            w0 = xrow[n0];     h0 = jg4[n0];
        }
        int c0 = base + 2 * tid;
        f32x4 o0, o1;
        o0.x = qdq(v0.x, lp[g0.x]);
        o0.y = qdq(v0.y, lp[g0.y]);
        o0.z = qdq(v0.z, lp[g0.z]);
        o0.w = qdq(v0.w, lp[g0.w]);
        o1.x = qdq(v1.x, lp[g1.x]);
        o1.y = qdq(v1.y, lp[g1.y]);
        o1.z = qdq(v1.z, lp[g1.z]);
        o1.w = qdq(v1.w, lp[g1.w]);
        __builtin_nontemporal_store(o0, &orow[c0]);
        __builtin_nontemporal_store(o1, &orow[c0 + 1]);
        v0 = w0; v1 = w1; g0 = h0; g1 = h1;
        base += 512;
    }
    // tail: 192 float4 at [2560, 2752)
    if (tid < NV - NFULL * 512) {
        f32x4 o0;
        o0.x = qdq(v0.x, lp[g0.x]);
        o0.y = qdq(v0.y, lp[g0.y]);
        o0.z = qdq(v0.z, lp[g0.z]);
        o0.w = qdq(v0.w, lp[g0.w]);
        __builtin_nontemporal_store(o0, &orow[NFULL * 512 + tid]);
    }
}

// ---------------------------------------------------------------------------
// Launch
// Inputs (setup_inputs order): 0=x, 1=scale, 2=zero_point, 3=qmax,
//                              4=col_order (unused), 5=invcol
// ---------------------------------------------------------------------------
extern "C" void kernel_launch(void* const* d_in, const int* in_sizes, int n_in,
                              void* d_out, int out_size, void* d_ws, size_t ws_size,
                              hipStream_t stream) {
    const float*   x     = (const float*)d_in[0];
    const float*   scale = (const float*)d_in[1];
    const float*   zp    = (const float*)d_in[2];
    const int32_t* qmax  = (const int32_t*)d_in[3];
    const int32_t* invc  = (const int32_t*)d_in[5];
    float*         out   = (float*)d_out;
    uint8_t*       jgrp  = (uint8_t*)d_ws;   // 11008 bytes

    build_jgrp_kernel<<<(COLS + 255) / 256, 256, 0, stream>>>(invc, jgrp);
    quantdeq_kernel<<<ROWS, 256, 0, stream>>>(x, scale, zp, qmax, jgrp, out);
}

// Round 7
// 65.359 us; speedup vs baseline: 1.1288x; 1.1288x over previous
//
#include <hip/hip_runtime.h>
#include <stdint.h>
#include <math.h>

#define ROWS 4096
#define COLS 11008
#define GPR  86            // groups per row
#define NV   (COLS / 4)    // 2752 float4 per row

typedef float f32x4 __attribute__((ext_vector_type(4)));

// ---------------------------------------------------------------------------
// Kernel 1: build jgrp[k] = invcol[k] >> 7  (uint8, 0..85) into d_ws.
// int64-vs-int32 detection: for little-endian int64 values < 2^32 every odd
// int32 word is 0; an int32 permutation of 0..11007 has at most one zero
// among the 16 sampled odd words.
// ---------------------------------------------------------------------------
__global__ void build_jgrp_kernel(const int32_t* __restrict__ invcol_raw,
                                  uint8_t* __restrict__ jgrp) {
    bool is64 = true;
    #pragma unroll
    for (int i = 1; i < 32; i += 2) {
        if (invcol_raw[i] != 0) { is64 = false; }
    }
    int k = blockIdx.x * blockDim.x + threadIdx.x;
    if (k < COLS) {
        int j = is64 ? invcol_raw[2 * k] : invcol_raw[k];
        jgrp[k] = (uint8_t)(j >> 7);
    }
}

// ---------------------------------------------------------------------------
// Kernel 2: elementwise quant-dequant, f64-round-faithful, rcp fast path,
// depth-2 software pipeline with CONTIGUOUS stride-256 indexing (R6 lesson:
// pairing adjacent float4 per thread makes each load instruction stride-32B
// across lanes -> 2KB sparse window per transaction -> 13% regression; here
// every global_load_dwordx4 stays a dense 1KB segment and we get 2 loads in
// flight by prefetching two loop iterations ahead instead).
//   out = clip(round(x/s), -rzp, qmax-rzp) * s     (exact: ints < 2^24)
// Fast path: q0 = x*(1/s); if within ~10 ulp of a half-integer boundary
// (rate ~7e-6) redo in f64 (absmax 0.0 in R3/R5/R6).
// ---------------------------------------------------------------------------
__device__ __forceinline__ float qdq(float v, float4 p) {
    float q0 = __fmul_rn(v, p.y);
    float t  = rintf(q0);
    float d  = fabsf(fabsf(q0 - t) - 0.5f);         // distance to nearest x.5
    if (d <= fabsf(q0) * 1.2e-6f + 1e-30f) {        // ~10 ulp guard band
        t = (float)rint((double)v / (double)p.x);   // |t| < 2^24: cast exact
    }
    t = fminf(fmaxf(t, p.z), p.w);
    return __fmul_rn(t, p.x);
}

__global__ __launch_bounds__(256) void quantdeq_kernel(
        const float*   __restrict__ x,
        const float*   __restrict__ scale,
        const float*   __restrict__ zp,
        const int32_t* __restrict__ qmax,
        const uint8_t* __restrict__ jgrp,
        float*         __restrict__ out) {
    __shared__ float4 lp[GPR];

    const int row = blockIdx.x;
    const int tid = threadIdx.x;

    if (tid < GPR) {
        const int gi = row * GPR + tid;
        float s   = fminf(fmaxf(scale[gi], 1e-4f), 1e4f);
        float rs  = __fdiv_rn(1.0f, s);
        float qmf = (float)qmax[gi];
        float rzp = fminf(fmaxf(rintf(zp[gi]), 0.0f), qmf);
        lp[tid] = make_float4(s, rs, -rzp, qmf - rzp);
    }
    __syncthreads();

    const float4* __restrict__ xrow = reinterpret_cast<const float4*>(x + (size_t)row * COLS);
    f32x4*        __restrict__ orow = reinterpret_cast<f32x4*>(out + (size_t)row * COLS);
    const uchar4* __restrict__ jg4  = reinterpret_cast<const uchar4*>(jgrp);

    // depth-2 pipeline: while computing index t, loads for t+256 and t+512
    // are in flight. Trip count per thread: 11 (tid<192) or 10 (tid>=192);
    // NV=2752 >= 512 so the two-stage prologue is always safe.
    int    t  = tid;
    const int n = (NV - tid + 255) / 256;   // >= 10
    float4 va = xrow[t],       vb = xrow[t + 256];
    uchar4 ga = jg4[t],        gb = jg4[t + 256];

    for (int i = 0; i + 2 < n; ++i) {
        const int tn = t + 512;
        float4 vc = xrow[tn];
        uchar4 gc = jg4[tn];
        f32x4 o;
        o.x = qdq(va.x, lp[ga.x]);
        o.y = qdq(va.y, lp[ga.y]);
        o.z = qdq(va.z, lp[ga.z]);
        o.w = qdq(va.w, lp[ga.w]);
        __builtin_nontemporal_store(o, &orow[t]);
        va = vb; ga = gb; vb = vc; gb = gc;
        t += 256;
    }
    {   // drain stage A
        f32x4 o;
        o.x = qdq(va.x, lp[ga.x]);
        o.y = qdq(va.y, lp[ga.y]);
        o.z = qdq(va.z, lp[ga.z]);
        o.w = qdq(va.w, lp[ga.w]);
        __builtin_nontemporal_store(o, &orow[t]);
    }
    {   // drain stage B
        f32x4 o;
        o.x = qdq(vb.x, lp[gb.x]);
        o.y = qdq(vb.y, lp[gb.y]);
        o.z = qdq(vb.z, lp[gb.z]);
        o.w = qdq(vb.w, lp[gb.w]);
        __builtin_nontemporal_store(o, &orow[t + 256]);
    }
}

// ---------------------------------------------------------------------------
// Launch
// Inputs (setup_inputs order): 0=x, 1=scale, 2=zero_point, 3=qmax,
//                              4=col_order (unused), 5=invcol
// ---------------------------------------------------------------------------
extern "C" void kernel_launch(void* const* d_in, const int* in_sizes, int n_in,
                              void* d_out, int out_size, void* d_ws, size_t ws_size,
                              hipStream_t stream) {
    const float*   x     = (const float*)d_in[0];
    const float*   scale = (const float*)d_in[1];
    const float*   zp    = (const float*)d_in[2];
    const int32_t* qmax  = (const int32_t*)d_in[3];
    const int32_t* invc  = (const int32_t*)d_in[5];
    float*         out   = (float*)d_out;
    uint8_t*       jgrp  = (uint8_t*)d_ws;   // 11008 bytes

    build_jgrp_kernel<<<(COLS + 255) / 256, 256, 0, stream>>>(invc, jgrp);
    quantdeq_kernel<<<ROWS, 256, 0, stream>>>(x, scale, zp, qmax, jgrp, out);
}

// Round 8
// 64.686 us; speedup vs baseline: 1.1405x; 1.0104x over previous
//
#include <hip/hip_runtime.h>
#include <stdint.h>
#include <math.h>

#define ROWS 4096
#define COLS 11008
#define GPR  86            // groups per row
#define NV   (COLS / 4)    // 2752 float4 per row
#define NFULL 10           // full unrolled iters; tail = 192 lanes (tid<192)
#define TAIL (NV - NFULL * 256)   // 192

typedef float f32x4 __attribute__((ext_vector_type(4)));

// ---------------------------------------------------------------------------
// Kernel 1: build jgrp[k] = invcol[k] >> 7  (uint8, 0..85) into d_ws.
// int64-vs-int32 detection: for little-endian int64 values < 2^32 every odd
// int32 word is 0; an int32 permutation of 0..11007 has at most one zero
// among the 16 sampled odd words.
// ---------------------------------------------------------------------------
__global__ void build_jgrp_kernel(const int32_t* __restrict__ invcol_raw,
                                  uint8_t* __restrict__ jgrp) {
    bool is64 = true;
    #pragma unroll
    for (int i = 1; i < 32; i += 2) {
        if (invcol_raw[i] != 0) { is64 = false; }
    }
    int k = blockIdx.x * blockDim.x + threadIdx.x;
    if (k < COLS) {
        int j = is64 ? invcol_raw[2 * k] : invcol_raw[k];
        jgrp[k] = (uint8_t)(j >> 7);
    }
}

// ---------------------------------------------------------------------------
// Kernel 2: elementwise quant-dequant, f64-round-faithful, rcp fast path.
//   out = clip(round(x/s), -rzp, qmax-rzp) * s     (exact: ints < 2^24)
// R8 change: all 11 uchar4 group-index words hoisted into registers at block
// start (static indexing only — runtime-indexed reg arrays spill to scratch),
// removing 10 vmem loads/thread from the loop and breaking the per-iteration
// vmem->ds_read dependency chain so param ds_reads can pipeline freely.
// Depth-2 contiguous x-prefetch kept (R6 lesson: per-instruction contiguity
// is sacred; R7 lesson: x-load MLP alone is not the limiter).
// Fast path: q0 = x*(1/s); if within ~10 ulp of a half-integer boundary
// (rate ~7e-6) redo in f64 (absmax 0.0 in R3/R5/R6/R7).
// ---------------------------------------------------------------------------
__device__ __forceinline__ float qdq(float v, float4 p) {
    float q0 = __fmul_rn(v, p.y);
    float t  = rintf(q0);
    float d  = fabsf(fabsf(q0 - t) - 0.5f);         // distance to nearest x.5
    if (d <= fabsf(q0) * 1.2e-6f + 1e-30f) {        // ~10 ulp guard band
        t = (float)rint((double)v / (double)p.x);   // |t| < 2^24: cast exact
    }
    t = fminf(fmaxf(t, p.z), p.w);
    return __fmul_rn(t, p.x);
}

__device__ __forceinline__ f32x4 qdq4(float4 v, uchar4 g, const float4* lp) {
    f32x4 o;
    o.x = qdq(v.x, lp[g.x]);
    o.y = qdq(v.y, lp[g.y]);
    o.z = qdq(v.z, lp[g.z]);
    o.w = qdq(v.w, lp[g.w]);
    return o;
}

__global__ __launch_bounds__(256) void quantdeq_kernel(
        const float*   __restrict__ x,
        const float*   __restrict__ scale,
        const float*   __restrict__ zp,
        const int32_t* __restrict__ qmax,
        const uint8_t* __restrict__ jgrp,
        float*         __restrict__ out) {
    __shared__ float4 lp[GPR];

    const int row = blockIdx.x;
    const int tid = threadIdx.x;

    if (tid < GPR) {
        const int gi = row * GPR + tid;
        float s   = fminf(fmaxf(scale[gi], 1e-4f), 1e4f);
        float rs  = __fdiv_rn(1.0f, s);
        float qmf = (float)qmax[gi];
        float rzp = fminf(fmaxf(rintf(zp[gi]), 0.0f), qmf);
        lp[tid] = make_float4(s, rs, -rzp, qmf - rzp);
    }

    const float4* __restrict__ xrow = reinterpret_cast<const float4*>(x + (size_t)row * COLS);
    f32x4*        __restrict__ orow = reinterpret_cast<f32x4*>(out + (size_t)row * COLS);
    const uchar4* __restrict__ jg4  = reinterpret_cast<const uchar4*>(jgrp);

    const bool has_tail = (tid < TAIL);

    // Hoist ALL group indices for this thread into registers (one burst of
    // 10-11 dword loads, L2-resident table). Static indexing throughout.
    uchar4 gr[NFULL + 1];
    #pragma unroll
    for (int i = 0; i < NFULL; ++i) gr[i] = jg4[tid + 256 * i];
    if (has_tail) gr[NFULL] = jg4[tid + 256 * NFULL];

    __syncthreads();

    // depth-2 x pipeline over compile-time-unrolled iterations
    float4 va = xrow[tid];
    float4 vb = xrow[tid + 256];

    #pragma unroll
    for (int i = 0; i < NFULL; ++i) {
        float4 vc;
        if (i + 2 < NFULL) {
            vc = xrow[tid + 256 * (i + 2)];
        } else if (i + 2 == NFULL) {
            if (has_tail) vc = xrow[tid + 256 * NFULL];
        }
        f32x4 o = qdq4(va, gr[i], lp);
        __builtin_nontemporal_store(o, &orow[tid + 256 * i]);
        va = vb; vb = vc;
    }
    if (has_tail) {
        f32x4 o = qdq4(va, gr[NFULL], lp);
        __builtin_nontemporal_store(o, &orow[tid + 256 * NFULL]);
    }
}

// ---------------------------------------------------------------------------
// Launch
// Inputs (setup_inputs order): 0=x, 1=scale, 2=zero_point, 3=qmax,
//                              4=col_order (unused), 5=invcol
// ---------------------------------------------------------------------------
extern "C" void kernel_launch(void* const* d_in, const int* in_sizes, int n_in,
                              void* d_out, int out_size, void* d_ws, size_t ws_size,
                              hipStream_t stream) {
    const float*   x     = (const float*)d_in[0];
    const float*   scale = (const float*)d_in[1];
    const float*   zp    = (const float*)d_in[2];
    const int32_t* qmax  = (const int32_t*)d_in[3];
    const int32_t* invc  = (const int32_t*)d_in[5];
    float*         out   = (float*)d_out;
    uint8_t*       jgrp  = (uint8_t*)d_ws;   // 11008 bytes

    build_jgrp_kernel<<<(COLS + 255) / 256, 256, 0, stream>>>(invc, jgrp);
    quantdeq_kernel<<<ROWS, 256, 0, stream>>>(x, scale, zp, qmax, jgrp, out);
}

// Round 10
// 64.572 us; speedup vs baseline: 1.1425x; 1.0018x over previous
//
#include <hip/hip_runtime.h>
#include <stdint.h>
#include <math.h>

#define ROWS 4096
#define COLS 11008
#define GPR  86            // groups per row
#define NV   (COLS / 4)    // 2752 float4 per row
#define NFULL 10           // full unrolled iters; tail = 192 lanes (tid<192)
#define TAIL (NV - NFULL * 256)   // 192

typedef float f32x4 __attribute__((ext_vector_type(4)));

// ---------------------------------------------------------------------------
// Kernel 1: build jgrp[k] = invcol[k] >> 7  (uint8, 0..85) into d_ws.
// int64-vs-int32 detection: for little-endian int64 values < 2^32 every odd
// int32 word is 0; an int32 permutation of 0..11007 has at most one zero
// among the 16 sampled odd words.
// ---------------------------------------------------------------------------
__global__ void build_jgrp_kernel(const int32_t* __restrict__ invcol_raw,
                                  uint8_t* __restrict__ jgrp) {
    bool is64 = true;
    #pragma unroll
    for (int i = 1; i < 32; i += 2) {
        if (invcol_raw[i] != 0) { is64 = false; }
    }
    int k = blockIdx.x * blockDim.x + threadIdx.x;
    if (k < COLS) {
        int j = is64 ? invcol_raw[2 * k] : invcol_raw[k];
        jgrp[k] = (uint8_t)(j >> 7);
    }
}

// ---------------------------------------------------------------------------
// Kernel 2: elementwise quant-dequant, f64-round-faithful, rcp fast path.
//   out = clip(round(x/s), -rzp, qmax-rzp) * s     (exact: ints < 2^24)
// Best structure (R8, 64.69 us): group indices hoisted to registers (static
// indexing), depth-2 contiguous x-prefetch, builtin nontemporal stores.
// R9 lesson: inline-asm VMEM stores have a store-data register hazard (the
// compiler reuses asm operand VGPRs before the store hardware reads them) —
// and nt was already set by the builtin anyway (FETCH pinned at 91 MB: L3
// write-allocate displacement of x is not software-controllable here).
// Fast path: q0 = x*(1/s); if within ~10 ulp of a half-integer boundary
// (rate ~7e-6) redo in f64 (absmax 0.0 in R3/R5/R6/R7/R8).
// ---------------------------------------------------------------------------
__device__ __forceinline__ float qdq(float v, float4 p) {
    float q0 = __fmul_rn(v, p.y);
    float t  = rintf(q0);
    float d  = fabsf(fabsf(q0 - t) - 0.5f);         // distance to nearest x.5
    if (d <= fabsf(q0) * 1.2e-6f + 1e-30f) {        // ~10 ulp guard band
        t = (float)rint((double)v / (double)p.x);   // |t| < 2^24: cast exact
    }
    t = fminf(fmaxf(t, p.z), p.w);
    return __fmul_rn(t, p.x);
}

__device__ __forceinline__ f32x4 qdq4(float4 v, uchar4 g, const float4* lp) {
    f32x4 o;
    o.x = qdq(v.x, lp[g.x]);
    o.y = qdq(v.y, lp[g.y]);
    o.z = qdq(v.z, lp[g.z]);
    o.w = qdq(v.w, lp[g.w]);
    return o;
}

__global__ __launch_bounds__(256) void quantdeq_kernel(
        const float*   __restrict__ x,
        const float*   __restrict__ scale,
        const float*   __restrict__ zp,
        const int32_t* __restrict__ qmax,
        const uint8_t* __restrict__ jgrp,
        float*         __restrict__ out) {
    __shared__ float4 lp[GPR];

    const int row = blockIdx.x;
    const int tid = threadIdx.x;

    if (tid < GPR) {
        const int gi = row * GPR + tid;
        float s   = fminf(fmaxf(scale[gi], 1e-4f), 1e4f);
        float rs  = __fdiv_rn(1.0f, s);
        float qmf = (float)qmax[gi];
        float rzp = fminf(fmaxf(rintf(zp[gi]), 0.0f), qmf);
        lp[tid] = make_float4(s, rs, -rzp, qmf - rzp);
    }

    const float4* __restrict__ xrow = reinterpret_cast<const float4*>(x + (size_t)row * COLS);
    f32x4*        __restrict__ orow = reinterpret_cast<f32x4*>(out + (size_t)row * COLS);
    const uchar4* __restrict__ jg4  = reinterpret_cast<const uchar4*>(jgrp);

    const bool has_tail = (tid < TAIL);

    // Hoist ALL group indices for this thread into registers (one burst of
    // 10-11 dword loads, L2-resident table). Static indexing throughout.
    uchar4 gr[NFULL + 1];
    #pragma unroll
    for (int i = 0; i < NFULL; ++i) gr[i] = jg4[tid + 256 * i];
    if (has_tail) gr[NFULL] = jg4[tid + 256 * NFULL];

    __syncthreads();

    // depth-2 x pipeline over compile-time-unrolled iterations
    float4 va = xrow[tid];
    float4 vb = xrow[tid + 256];

    #pragma unroll
    for (int i = 0; i < NFULL; ++i) {
        float4 vc;
        if (i + 2 < NFULL) {
            vc = xrow[tid + 256 * (i + 2)];
        } else if (i + 2 == NFULL) {
            if (has_tail) vc = xrow[tid + 256 * NFULL];
        }
        f32x4 o = qdq4(va, gr[i], lp);
        __builtin_nontemporal_store(o, &orow[tid + 256 * i]);
        va = vb; vb = vc;
    }
    if (has_tail) {
        f32x4 o = qdq4(va, gr[NFULL], lp);
        __builtin_nontemporal_store(o, &orow[tid + 256 * NFULL]);
    }
}

// ---------------------------------------------------------------------------
// Launch
// Inputs (setup_inputs order): 0=x, 1=scale, 2=zero_point, 3=qmax,
//                              4=col_order (unused), 5=invcol
// ---------------------------------------------------------------------------
extern "C" void kernel_launch(void* const* d_in, const int* in_sizes, int n_in,
                              void* d_out, int out_size, void* d_ws, size_t ws_size,
                              hipStream_t stream) {
    const float*   x     = (const float*)d_in[0];
    const float*   scale = (const float*)d_in[1];
    const float*   zp    = (const float*)d_in[2];
    const int32_t* qmax  = (const int32_t*)d_in[3];
    const int32_t* invc  = (const int32_t*)d_in[5];
    float*         out   = (float*)d_out;
    uint8_t*       jgrp  = (uint8_t*)d_ws;   // 11008 bytes

    build_jgrp_kernel<<<(COLS + 255) / 256, 256, 0, stream>>>(invc, jgrp);
    quantdeq_kernel<<<ROWS, 256, 0, stream>>>(x, scale, zp, qmax, jgrp, out);
}